// Round 1
// 1072.259 us; speedup vs baseline: 1.0822x; 1.0822x over previous
//
#include <hip/hip_runtime.h>

typedef unsigned short u16;
typedef unsigned int u32;

#define BATCH 4
#define CDIM 384
#define IMG 128
#define HW 16384
#define QKVC 1152
#define NHEADS 8
#define CHD 48
#define DD2 96
#define KFIN 768
#define QSTRIDE ((size_t)75497472)   // element offset qkvx -> qkvm in ws

typedef __attribute__((ext_vector_type(8))) short bf16x8;
typedef __attribute__((ext_vector_type(4))) float f32x4;

// ---------- bf16 helpers (manual RNE) ----------
__device__ __forceinline__ u16 f2bf(float f){
  union { float f; u32 u; } v; v.f = f;
  u32 u = v.u;
  u32 r = (u + 0x7fffu + ((u >> 16) & 1u)) >> 16;
  return (u16)r;
}
__device__ __forceinline__ float bf2f(u16 h){
  union { u32 u; float f; } v; v.u = ((u32)h) << 16;
  return v.f;
}

// ---------- workspace layout (bytes) ----------
#define OFF_QKVX  ((size_t)0)                         // u16 [4][1152][16384]
#define OFF_QKVM  ((size_t)150994944)                 // u16 [4][1152][16384]
#define OFF_T     ((size_t)301989888)                 // u16 [1152][16384]  (bf16)
#define OFF_SSQ   ((size_t)339738624)                 // f32 [2][4][1152]
#define OFF_S     ((size_t)339775488)                 // f32 [2][4][8][48][96]
#define OFF_ATTN  ((size_t)340955136)                 // f32 [2][4][8][48][96]
#define OFF_AFINB ((size_t)342134784)                 // bf16 [4][384][768]
#define OFF_W2    ((size_t)344494080)                 // f32 [384][768]
#define OFF_B2    ((size_t)345673728)                 // f32 [384]
#define OFF_WB    ((size_t)345675264)                 // bf16 [1152][384]

// ---------- global_load_lds helper (16B per lane, dest = base + lane*16) ----------
typedef __attribute__((address_space(1))) const u32 gas_u32;
typedef __attribute__((address_space(3))) u32 las_u32;
__device__ __forceinline__ void gl_lds16(const u16* g, u16* l){
  __builtin_amdgcn_global_load_lds((gas_u32*)g, (las_u32*)l, 16, 0, 0);
}

// ---------- K0: W2 = proj_w @ lin_w ; b2 = proj_w @ lin_b ; Wb = bf16(qkv_w) ----------
__global__ void __launch_bounds__(256) k_w2(const float* __restrict__ proj,
                                            const float* __restrict__ lin,
                                            const float* __restrict__ linb,
                                            const float* __restrict__ qkvw,
                                            float* __restrict__ W2,
                                            float* __restrict__ b2,
                                            u16* __restrict__ Wb){
  int idx = blockIdx.x * 256 + threadIdx.x;
  if (idx < CDIM * KFIN){
    int o = idx / KFIN, d = idx % KFIN;
    float acc = 0.f;
    for (int c = 0; c < CDIM; c++)
      acc = fmaf(proj[o * CDIM + c], lin[c * KFIN + d], acc);
    W2[idx] = acc;
  }
  if (idx < CDIM){
    float acc = 0.f;
    for (int c = 0; c < CDIM; c++)
      acc = fmaf(proj[idx * CDIM + c], linb[c], acc);
    b2[idx] = acc;
  }
  if (idx < QKVC * CDIM) Wb[idx] = f2bf(qkvw[idx]);
}

// ---------- K_cvt: fp32 [c][n] -> bf16 [n][c] (k-contiguous B for the pointwise GEMM) ----------
// z in [0,8): z<4 -> x batch z ; z>=4 -> msg batch z-4. Bt lives in d_out (scratch until final GEMM).
__global__ void __launch_bounds__(256) k_cvt(const float* __restrict__ x,
                                             const float* __restrict__ msg,
                                             u16* __restrict__ Bt){
  int z = blockIdx.z;
  const float* src = (z < 4 ? x : msg) + (size_t)(z & 3) * CDIM * HW;
  u16* dst = Bt + (size_t)z * HW * CDIM;
  int nb = blockIdx.x * 64, cb = blockIdx.y * 64;
  __shared__ u16 t[64][65];
  int tid = threadIdx.x;
  #pragma unroll
  for (int i = 0; i < 16; i++){
    int idx = tid + i * 256;
    int c = idx >> 6, n = idx & 63;
    t[c][n] = f2bf(src[(size_t)(cb + c) * HW + nb + n]);
  }
  __syncthreads();
  u32* d32 = (u32*)dst;
  #pragma unroll
  for (int i = 0; i < 8; i++){
    int idx = tid + i * 256;
    int n = idx >> 5, cp = idx & 31;
    u32 v = (u32)t[2 * cp][n] | ((u32)t[2 * cp + 1][n] << 16);
    d32[((size_t)(nb + n) * CDIM + cb) / 2 + cp] = v;
  }
}

// ---------- K_pw: m97-structure bf16 GEMM: C[1152][16384] = Wb[1152][384] * Bt[16384][384]^T ----------
// Both operands k-contiguous; staged via global_load_lds width-16; XCD-swizzled grid (1152 = 8*144).
__global__ void __launch_bounds__(256) k_pw(const u16* __restrict__ A,
                                            const u16* __restrict__ B,
                                            u16* __restrict__ C){
  __shared__ __align__(16) u16 As[128 * 32];
  __shared__ __align__(16) u16 Bs[128 * 32];
  int orig = blockIdx.x;
  int swz = (orig & 7) * 144 + (orig >> 3);   // bijective: 1152 % 8 == 0
  int bx = swz % 9, by = swz / 9;             // bx: M-block (9), by: N-block (128)
  int m0 = bx * 128, n0 = by * 128;
  int tid = threadIdx.x;
  int w = tid >> 6, lane = tid & 63;
  int wy = w >> 1, wx = w & 1;
  int lm = lane & 15, q = lane >> 4;

  // staging geometry: wave w covers rows w*16 + lane/4 (and +64), cols (lane&3)*8
  int srow = w * 16 + (lane >> 2);
  int scol = (lane & 3) * 8;
  const u16* ga = A + (size_t)(m0 + srow) * CDIM + scol;
  const u16* gb = B + (size_t)(n0 + srow) * CDIM + scol;
  u16* la = &As[srow * 32 + scol];   // byte offset = w*1024 + lane*16 (linear per wave)
  u16* lb = &Bs[srow * 32 + scol];

  f32x4 acc[4][4];
  #pragma unroll
  for (int i = 0; i < 4; i++)
    #pragma unroll
    for (int j = 0; j < 4; j++) acc[i][j] = (f32x4){0.f,0.f,0.f,0.f};

  for (int k0 = 0; k0 < CDIM; k0 += 32){
    gl_lds16(ga + k0,             la);
    gl_lds16(ga + 64 * CDIM + k0, la + 64 * 32);
    gl_lds16(gb + k0,             lb);
    gl_lds16(gb + 64 * CDIM + k0, lb + 64 * 32);
    __syncthreads();   // vmcnt(0) drain before use
    bf16x8 af[4], bfr[4];
    #pragma unroll
    for (int i = 0; i < 4; i++)
      af[i] = *(const bf16x8*)&As[(wy * 64 + i * 16 + lm) * 32 + q * 8];
    #pragma unroll
    for (int j = 0; j < 4; j++)
      bfr[j] = *(const bf16x8*)&Bs[(wx * 64 + j * 16 + lm) * 32 + q * 8];
    #pragma unroll
    for (int i = 0; i < 4; i++)
      #pragma unroll
      for (int j = 0; j < 4; j++)
        acc[i][j] = __builtin_amdgcn_mfma_f32_16x16x32_bf16(af[i], bfr[j], acc[i][j], 0, 0, 0);
    __syncthreads();
  }
  // epilogue: C[row][col], col = lane&15, row = quad*4 + reg (same mapping as verified kernel)
  #pragma unroll
  for (int i = 0; i < 4; i++){
    #pragma unroll
    for (int r = 0; r < 4; r++){
      int row = m0 + wy * 64 + i * 16 + q * 4 + r;
      u16* cp = C + (size_t)row * HW + n0 + wx * 64 + lm;
      #pragma unroll
      for (int j = 0; j < 4; j++)
        cp[j * 16] = f2bf(acc[i][j][r]);
    }
  }
}

// ---------- vc row mapping: dd in [0,768) -> v row pointer ----------
__device__ __forceinline__ const u16* vc_row(const u16* qbase, int bz, int dd){
  int h = dd / DD2;
  int e = dd - h * DD2;
  const u16* p = qbase + (e < CHD ? (size_t)0 : QSTRIDE);
  int c = (e < CHD) ? e : (e - CHD);
  return p + ((size_t)bz * QKVC + 2 * CDIM + h * CHD + c) * HW;
}

// ---------- K1: bf16 MFMA GEMM  C[M][N] = A[M][K] * B[K][N], N=16384 fixed ----------
// BMODE 0: Bsrc = fp32 rows (pointwise conv); BMODE 1: Bsrc = u16 qkvx base, rows via vc_row
// CBF16 1: store bf16 C; else fp32 (+bias)
template<int BMODE, int CBF16>
__global__ void __launch_bounds__(256) k_mfma_gemm(
    const u16* __restrict__ A, const void* __restrict__ Bsrc,
    const float* __restrict__ bias, void* __restrict__ Cv, int M, int K){
  __shared__ __align__(16) u16 As[128][40];
  __shared__ __align__(16) u16 Bs[128][40];
  int tid = threadIdx.x;
  int m0 = blockIdx.x * 128, n0 = blockIdx.y * 128;
  int bz = blockIdx.z;
  size_t cofs = 0;
  if (BMODE == 1){
    A += (size_t)bz * M * K;
    cofs = (size_t)bz * (size_t)M * HW;
  }
  int kp = tid & 15, ng = tid >> 4;       // B staging: k-pair, n-group
  int arow = tid >> 1, ah = tid & 1;      // A staging
  int w = tid >> 6, lane = tid & 63;
  int wy = w >> 1, wx = w & 1;
  int lm = lane & 15, q = lane >> 4;

  f32x4 acc[4][4];
  #pragma unroll
  for (int i = 0; i < 4; i++)
    #pragma unroll
    for (int j = 0; j < 4; j++) acc[i][j] = (f32x4){0.f,0.f,0.f,0.f};

  for (int k0 = 0; k0 < K; k0 += 32){
    // ---- stage B (transpose to k-major) ----
    if (BMODE == 0){
      const float* r0 = (const float*)Bsrc + (size_t)(k0 + 2*kp) * HW + n0 + ng*8;
      const float* r1 = r0 + HW;
      float4 x0 = *(const float4*)r0;
      float4 x1 = *(const float4*)(r0 + 4);
      float4 y0 = *(const float4*)r1;
      float4 y1 = *(const float4*)(r1 + 4);
      float e0[8] = {x0.x,x0.y,x0.z,x0.w,x1.x,x1.y,x1.z,x1.w};
      float e1[8] = {y0.x,y0.y,y0.z,y0.w,y1.x,y1.y,y1.z,y1.w};
      #pragma unroll
      for (int j = 0; j < 8; j++){
        u32 pk = (u32)f2bf(e0[j]) | ((u32)f2bf(e1[j]) << 16);
        *(u32*)&Bs[ng*8 + j][2*kp] = pk;
      }
    } else {
      const u16* r0 = vc_row((const u16*)Bsrc, bz, k0 + 2*kp)     + n0 + ng*8;
      const u16* r1 = vc_row((const u16*)Bsrc, bz, k0 + 2*kp + 1) + n0 + ng*8;
      uint4 u0 = *(const uint4*)r0;
      uint4 u1 = *(const uint4*)r1;
      u32 aa[4] = {u0.x, u0.y, u0.z, u0.w};
      u32 bb[4] = {u1.x, u1.y, u1.z, u1.w};
      #pragma unroll
      for (int j = 0; j < 8; j++){
        u32 lo = (aa[j >> 1] >> (16 * (j & 1))) & 0xffffu;
        u32 hi = (bb[j >> 1] >> (16 * (j & 1))) & 0xffffu;
        *(u32*)&Bs[ng*8 + j][2*kp] = lo | (hi << 16);
      }
    }
    // ---- stage A (already k-major) ----
    {
      const u16* ap = A + (size_t)(m0 + arow) * K + k0 + ah*16;
      uint4 a0 = *(const uint4*)ap;
      uint4 a1 = *(const uint4*)(ap + 8);
      *(uint4*)&As[arow][ah*16]     = a0;
      *(uint4*)&As[arow][ah*16 + 8] = a1;
    }
    __syncthreads();
    // ---- fragments + MFMA ----
    bf16x8 af[4], bfr[4];
    #pragma unroll
    for (int i = 0; i < 4; i++)
      af[i] = *(const bf16x8*)&As[wy*64 + i*16 + lm][q*8];
    #pragma unroll
    for (int j = 0; j < 4; j++)
      bfr[j] = *(const bf16x8*)&Bs[wx*64 + j*16 + lm][q*8];
    #pragma unroll
    for (int i = 0; i < 4; i++)
      #pragma unroll
      for (int j = 0; j < 4; j++)
        acc[i][j] = __builtin_amdgcn_mfma_f32_16x16x32_bf16(af[i], bfr[j], acc[i][j], 0, 0, 0);
    __syncthreads();
  }
  // ---- epilogue: C[row][col], col=lane&15, row=quad*4+reg ----
  #pragma unroll
  for (int i = 0; i < 4; i++){
    #pragma unroll
    for (int r = 0; r < 4; r++){
      int row = m0 + wy*64 + i*16 + q*4 + r;
      if (CBF16){
        u16* cp = (u16*)Cv + (size_t)row * HW + n0 + wx*64 + lm;
        #pragma unroll
        for (int j = 0; j < 4; j++)
          cp[j*16] = f2bf(acc[i][j][r]);
      } else {
        float bv = bias ? bias[row] : 0.f;
        float* cp = (float*)Cv + cofs + (size_t)row * HW + n0 + wx*64 + lm;
        #pragma unroll
        for (int j = 0; j < 4; j++)
          cp[j*16] = acc[i][j][r] + bv;
      }
    }
  }
}

// ---------- K2: depthwise 3x3 (bf16 in) + bf16 store + per-channel sum-of-squares ----------
__global__ void __launch_bounds__(256) k_dw(const u16* __restrict__ T,
                                            const float* __restrict__ dw,
                                            u16* __restrict__ qkv,
                                            float* __restrict__ ssq){
  int ch = blockIdx.x;
  int rg = blockIdx.y;
  __shared__ float tile[1280];
  __shared__ float red[256];
  int tid = threadIdx.x;
  int r0 = rg * 8;
  for (int i = tid; i < 1280; i += 256){
    int r = r0 - 1 + i / 128;
    int cx = i % 128;
    tile[i] = (r >= 0 && r < IMG) ? bf2f(T[(size_t)ch * HW + r * IMG + cx]) : 0.f;
  }
  __syncthreads();
  float w[9];
  #pragma unroll
  for (int t = 0; t < 9; t++) w[t] = dw[ch * 9 + t];
  float ss = 0.f;
  #pragma unroll
  for (int p = 0; p < 4; p++){
    int px = tid + p * 256;
    int rr = px >> 7, x = px & 127;
    float a = 0.f;
    #pragma unroll
    for (int dy = 0; dy < 3; dy++)
      #pragma unroll
      for (int dx = 0; dx < 3; dx++){
        int xx = x + dx - 1;
        if (xx >= 0 && xx < IMG)
          a = fmaf(tile[(rr + dy) * IMG + xx], w[dy * 3 + dx], a);
      }
    qkv[(size_t)ch * HW + (r0 + rr) * IMG + x] = f2bf(a);
    ss = fmaf(a, a, ss);
  }
  red[tid] = ss;
  __syncthreads();
  for (int s = 128; s > 0; s >>= 1){
    if (tid < s) red[tid] += red[tid + s];
    __syncthreads();
  }
  if (tid == 0) atomicAdd(&ssq[ch], red[0]);
}

// ---------- K3: logits via MFMA, fragments straight from global (both operands k-contiguous) ----------
// S[iq*48+c][d] per (b,h); 96x96 output, K=16384 split into 16 chunks, f32 atomicAdd combine.
#define LCHUNK 1024
__global__ void __launch_bounds__(256) k_logits_mfma(const u16* __restrict__ qkvx,
                                                     const u16* __restrict__ qkvm,
                                                     float* __restrict__ S){
  int nc = blockIdx.x;               // 0..15
  int bh = blockIdx.y;               // 0..31
  int b = bh & 3, h = bh >> 2;
  int tid = threadIdx.x;
  int w = tid >> 6, lane = tid & 63;
  int wy = w >> 1, wx = w & 1;       // wave covers rows wy*48..+48, cols wx*48..+48
  int lm = lane & 15, quad = lane >> 4;

  const u16* ap[3]; const u16* bp[3];
  #pragma unroll
  for (int i = 0; i < 3; i++){
    int g = wy * 48 + i * 16 + lm;         // q-global-row in [0,96)
    int c = (g < 48) ? g : g - 48;
    ap[i] = ((g < 48) ? qkvx : qkvm) + ((size_t)b * QKVC + h * CHD + c) * HW;
    int d = wx * 48 + i * 16 + lm;         // k_c col in [0,96)
    int cc = (d < 48) ? d : d - 48;
    bp[i] = ((d < 48) ? qkvx : qkvm) + ((size_t)b * QKVC + CDIM + h * CHD + cc) * HW;
  }
  f32x4 acc[3][3];
  #pragma unroll
  for (int i = 0; i < 3; i++)
    #pragma unroll
    for (int j = 0; j < 3; j++) acc[i][j] = (f32x4){0.f,0.f,0.f,0.f};

  int nbeg = nc * LCHUNK + quad * 8;
  int nend = nc * LCHUNK + LCHUNK;
  for (int n = nbeg; n < nend; n += 32){
    bf16x8 af[3], bfr[3];
    #pragma unroll
    for (int i = 0; i < 3; i++) af[i]  = *(const bf16x8*)(ap[i] + n);
    #pragma unroll
    for (int j = 0; j < 3; j++) bfr[j] = *(const bf16x8*)(bp[j] + n);
    #pragma unroll
    for (int i = 0; i < 3; i++)
      #pragma unroll
      for (int j = 0; j < 3; j++)
        acc[i][j] = __builtin_amdgcn_mfma_f32_16x16x32_bf16(af[i], bfr[j], acc[i][j], 0, 0, 0);
  }
  #pragma unroll
  for (int i = 0; i < 3; i++){
    #pragma unroll
    for (int r = 0; r < 4; r++){
      int g = wy * 48 + i * 16 + quad * 4 + r;
      int iq = (g >= 48) ? 1 : 0;
      int c = iq ? g - 48 : g;
      float* Sp = S + (((size_t)(iq * BATCH + b) * NHEADS + h) * CHD + c) * DD2;
      #pragma unroll
      for (int j = 0; j < 3; j++)
        atomicAdd(&Sp[wx * 48 + j * 16 + lm], acc[i][j][r]);
    }
  }
}

// ---------- K4a: scale by norms+temperature, softmax over d ----------
__global__ void __launch_bounds__(128) k_softmax(const float* __restrict__ S,
                                                 const float* __restrict__ ssq,
                                                 const float* __restrict__ temp,
                                                 float* __restrict__ attn){
  int row = blockIdx.x;
  int c = row % CHD;
  int h = (row / CHD) % NHEADS;
  int b = (row / (CHD * NHEADS)) % BATCH;
  int iq = row / (CHD * NHEADS * BATCH);
  int tid = threadIdx.x;
  __shared__ float sh[128];
  const float* Sp = S + (size_t)row * DD2;
  float ssq_q = ssq[(iq * BATCH + b) * QKVC + h * CHD + c];
  float nq = fmaxf(sqrtf(ssq_q), 1e-12f);
  float tmp = temp[h];
  float logit = -1e30f;
  int d = tid;
  if (d < DD2){
    float ssq_k = ssq[((d < CHD ? 0 : 1) * BATCH + b) * QKVC + CDIM + h * CHD + (d % CHD)];
    float nk = fmaxf(sqrtf(ssq_k), 1e-12f);
    logit = Sp[d] * tmp / (nq * nk);
  }
  sh[tid] = logit; __syncthreads();
  for (int s = 64; s > 0; s >>= 1){
    if (tid < s) sh[tid] = fmaxf(sh[tid], sh[tid + s]);
    __syncthreads();
  }
  float mx = sh[0]; __syncthreads();
  float e = (d < DD2) ? expf(logit - mx) : 0.f;
  sh[tid] = e; __syncthreads();
  for (int s = 64; s > 0; s >>= 1){
    if (tid < s) sh[tid] += sh[tid + s];
    __syncthreads();
  }
  float sum = sh[0];
  if (d < DD2) attn[(size_t)row * DD2 + d] = e / sum;
}

// ---------- K4b: AfinB (bf16) = W2-folded attention ----------
__global__ void __launch_bounds__(128) k_mmat(const float* __restrict__ attn,
                                              const float* __restrict__ W2,
                                              u16* __restrict__ AfinB){
  int oz = blockIdx.x;
  int h = blockIdx.y;
  int b = blockIdx.z;
  __shared__ float a1[CHD * DD2];
  __shared__ float a2[CHD * DD2];
  int tid = threadIdx.x;
  const float* A1 = attn + ((size_t)(0 * BATCH + b) * NHEADS + h) * CHD * DD2;
  const float* A2 = attn + ((size_t)(1 * BATCH + b) * NHEADS + h) * CHD * DD2;
  for (int i = tid; i < CHD * DD2; i += 128){ a1[i] = A1[i]; a2[i] = A2[i]; }
  __syncthreads();
  int e = tid;
  if (e < DD2){
    for (int oo = 0; oo < 8; oo++){
      int o = oz * 8 + oo;
      float acc = 0.f;
      #pragma unroll 4
      for (int cc = 0; cc < CHD; cc++){
        acc = fmaf(W2[o * KFIN + h * CHD + cc],        a1[cc * DD2 + e], acc);
        acc = fmaf(W2[o * KFIN + CDIM + h * CHD + cc], a2[cc * DD2 + e], acc);
      }
      AfinB[((size_t)b * CDIM + o) * KFIN + h * DD2 + e] = f2bf(acc);
    }
  }
}

extern "C" void kernel_launch(void* const* d_in, const int* in_sizes, int n_in,
                              void* d_out, int out_size, void* d_ws, size_t ws_size,
                              hipStream_t stream){
  const float* x      = (const float*)d_in[0];
  const float* msg    = (const float*)d_in[1];
  const float* temp   = (const float*)d_in[2];
  const float* qkv_w  = (const float*)d_in[3];
  const float* dw_w   = (const float*)d_in[4];
  const float* proj_w = (const float*)d_in[5];
  const float* lin_w  = (const float*)d_in[6];
  const float* lin_b  = (const float*)d_in[7];
  float* out = (float*)d_out;

  char* ws = (char*)d_ws;
  u16*   qkvx  = (u16*)(ws + OFF_QKVX);
  u16*   qkvm  = (u16*)(ws + OFF_QKVM);
  u16*   T     = (u16*)(ws + OFF_T);
  float* ssq   = (float*)(ws + OFF_SSQ);
  float* S     = (float*)(ws + OFF_S);
  float* attn  = (float*)(ws + OFF_ATTN);
  u16*   AfinB = (u16*)(ws + OFF_AFINB);
  float* W2    = (float*)(ws + OFF_W2);
  float* b2    = (float*)(ws + OFF_B2);
  u16*   Wb    = (u16*)(ws + OFF_WB);

  // Bt scratch lives in d_out: 8 * 16384 * 384 * 2 B == out_size exactly.
  // It is fully consumed by the 8 k_pw dispatches before the final GEMM overwrites out.
  u16* Bt = (u16*)d_out;

  hipMemsetAsync(ws + OFF_SSQ, 0, (OFF_ATTN - OFF_SSQ), stream);

  k_w2<<<dim3((QKVC * CDIM + 255) / 256), dim3(256), 0, stream>>>(
      proj_w, lin_w, lin_b, qkv_w, W2, b2, Wb);

  k_cvt<<<dim3(HW / 64, CDIM / 64, 8), dim3(256), 0, stream>>>(x, msg, Bt);

  for (int z = 0; z < 8; z++){
    int inp = z >> 2, bb = z & 3;
    u16* qdst = (inp ? qkvm : qkvx) + (size_t)bb * QKVC * HW;
    k_pw<<<dim3(QKVC / 128 * (HW / 128)), dim3(256), 0, stream>>>(
        Wb, Bt + (size_t)z * HW * CDIM, T);
    k_dw<<<dim3(QKVC, IMG / 8), dim3(256), 0, stream>>>(
        T, dw_w, qdst, ssq + (size_t)z * QKVC);
  }

  k_logits_mfma<<<dim3(16, 32), dim3(256), 0, stream>>>(qkvx, qkvm, S);
  k_softmax<<<dim3(2 * BATCH * NHEADS * CHD), dim3(128), 0, stream>>>(S, ssq, temp, attn);
  k_mmat<<<dim3(CDIM / 8, NHEADS, BATCH), dim3(128), 0, stream>>>(attn, W2, AfinB);
  k_mfma_gemm<1, 0><<<dim3(CDIM / 128, HW / 128, BATCH), dim3(256), 0, stream>>>(
      AfinB, qkvx, b2, out, CDIM, KFIN);
}

// Round 2
// 1016.786 us; speedup vs baseline: 1.1413x; 1.0546x over previous
//
#include <hip/hip_runtime.h>

typedef unsigned short u16;
typedef unsigned int u32;

#define BATCH 4
#define CDIM 384
#define IMG 128
#define HW 16384
#define QKVC 1152
#define NHEADS 8
#define CHD 48
#define DD2 96
#define KFIN 768

typedef __attribute__((ext_vector_type(8))) short bf16x8;
typedef __attribute__((ext_vector_type(4))) float f32x4;

// ---------- bf16 helpers (manual RNE) ----------
__device__ __forceinline__ u16 f2bf(float f){
  union { float f; u32 u; } v; v.f = f;
  u32 u = v.u;
  u32 r = (u + 0x7fffu + ((u >> 16) & 1u)) >> 16;
  return (u16)r;
}
__device__ __forceinline__ float bf2f(u16 h){
  union { u32 u; float f; } v; v.u = ((u32)h) << 16;
  return v.f;
}

// ---------- workspace layout (bytes) ----------
#define OFF_QKVX  ((size_t)0)                         // u16 [4][1152][16384]; v-slot (rows 768..1151) holds Vt0[b][n][384]
#define OFF_QKVM  ((size_t)150994944)                 // u16 [4][1152][16384]; v-slot holds Vt1[b][n][384]
#define OFF_T     ((size_t)301989888)                 // u16 [1152][16384]  (bf16)
#define OFF_SSQ   ((size_t)339738624)                 // f32 [2][4][1152] (only ch<768 written/read)
#define OFF_S     ((size_t)339775488)                 // f32 [2][4][8][48][96]
#define OFF_ATTN  ((size_t)340955136)                 // f32 [2][4][8][48][96]
#define OFF_AFINB ((size_t)342134784)                 // bf16 [4][384][768]
#define OFF_W2    ((size_t)344494080)                 // f32 [384][768]
#define OFF_B2    ((size_t)345673728)                 // f32 [384]
#define OFF_WB    ((size_t)345675264)                 // bf16 [1152][384]

// ---------- global_load_lds helper (16B per lane, dest = base + lane*16) ----------
typedef __attribute__((address_space(1))) const u32 gas_u32;
typedef __attribute__((address_space(3))) u32 las_u32;
__device__ __forceinline__ void gl_lds16(const u16* g, u16* l){
  __builtin_amdgcn_global_load_lds((gas_u32*)g, (las_u32*)l, 16, 0, 0);
}

// ---------- K0: W2 = proj_w @ lin_w ; b2 = proj_w @ lin_b ; Wb = bf16(qkv_w) ----------
__global__ void __launch_bounds__(256) k_w2(const float* __restrict__ proj,
                                            const float* __restrict__ lin,
                                            const float* __restrict__ linb,
                                            const float* __restrict__ qkvw,
                                            float* __restrict__ W2,
                                            float* __restrict__ b2,
                                            u16* __restrict__ Wb){
  int idx = blockIdx.x * 256 + threadIdx.x;
  if (idx < CDIM * KFIN){
    int o = idx / KFIN, d = idx % KFIN;
    float acc = 0.f;
    for (int c = 0; c < CDIM; c++)
      acc = fmaf(proj[o * CDIM + c], lin[c * KFIN + d], acc);
    W2[idx] = acc;
  }
  if (idx < CDIM){
    float acc = 0.f;
    for (int c = 0; c < CDIM; c++)
      acc = fmaf(proj[idx * CDIM + c], linb[c], acc);
    b2[idx] = acc;
  }
  if (idx < QKVC * CDIM) Wb[idx] = f2bf(qkvw[idx]);
}

// ---------- K_cvt: fp32 [c][n] -> bf16 [n][c] (k-contiguous B for the pointwise GEMM) ----------
__global__ void __launch_bounds__(256) k_cvt(const float* __restrict__ x,
                                             const float* __restrict__ msg,
                                             u16* __restrict__ Bt){
  int z = blockIdx.z;
  const float* src = (z < 4 ? x : msg) + (size_t)(z & 3) * CDIM * HW;
  u16* dst = Bt + (size_t)z * HW * CDIM;
  int nb = blockIdx.x * 64, cb = blockIdx.y * 64;
  __shared__ u16 t[64][65];
  int tid = threadIdx.x;
  #pragma unroll
  for (int i = 0; i < 16; i++){
    int idx = tid + i * 256;
    int c = idx >> 6, n = idx & 63;
    t[c][n] = f2bf(src[(size_t)(cb + c) * HW + nb + n]);
  }
  __syncthreads();
  u32* d32 = (u32*)dst;
  #pragma unroll
  for (int i = 0; i < 8; i++){
    int idx = tid + i * 256;
    int n = idx >> 5, cp = idx & 31;
    u32 v = (u32)t[2 * cp][n] | ((u32)t[2 * cp + 1][n] << 16);
    d32[((size_t)(nb + n) * CDIM + cb) / 2 + cp] = v;
  }
}

// ---------- K_pw: 2-phase dbuf bf16 GEMM: C[1152][16384] = Wb[1152][384] * Bt[16384][384]^T ----------
__global__ void __launch_bounds__(256) k_pw(const u16* __restrict__ A,
                                            const u16* __restrict__ B,
                                            u16* __restrict__ C){
  __shared__ __align__(16) u16 As[2 * 4096];
  __shared__ __align__(16) u16 Bs[2 * 4096];
  int orig = blockIdx.x;
  int swz = (orig & 7) * 144 + (orig >> 3);   // bijective: 1152 % 8 == 0
  int bx = swz % 9, by = swz / 9;             // bx: M-block (9), by: N-block (128)
  int m0 = bx * 128, n0 = by * 128;
  int tid = threadIdx.x;
  int w = tid >> 6, lane = tid & 63;
  int wy = w >> 1, wx = w & 1;
  int lm = lane & 15, q = lane >> 4;

  int srow = w * 16 + (lane >> 2);
  int scol = (lane & 3) * 8;
  const u16* ga = A + (size_t)(m0 + srow) * CDIM + scol;
  const u16* gb = B + (size_t)(n0 + srow) * CDIM + scol;
  u16* la = As + srow * 32 + scol;   // per-wave linear: w*1024 + lane*16 bytes
  u16* lb = Bs + srow * 32 + scol;

  f32x4 acc[4][4];
  #pragma unroll
  for (int i = 0; i < 4; i++)
    #pragma unroll
    for (int j = 0; j < 4; j++) acc[i][j] = (f32x4){0.f,0.f,0.f,0.f};

#define PW_STAGE(buf, k0) do{ \
    gl_lds16(ga + (k0),             la + (buf) * 4096); \
    gl_lds16(ga + 64*CDIM + (k0),   la + (buf) * 4096 + 2048); \
    gl_lds16(gb + (k0),             lb + (buf) * 4096); \
    gl_lds16(gb + 64*CDIM + (k0),   lb + (buf) * 4096 + 2048); \
  }while(0)

  PW_STAGE(0, 0);
  __syncthreads();
  int cur = 0;
  for (int t = 0; t < 12; t++){
    if (t < 11) PW_STAGE(cur ^ 1, (t + 1) * 32);
    bf16x8 af[4], bfr[4];
    #pragma unroll
    for (int i = 0; i < 4; i++)
      af[i] = *(const bf16x8*)&As[cur * 4096 + (wy * 64 + i * 16 + lm) * 32 + q * 8];
    #pragma unroll
    for (int j = 0; j < 4; j++)
      bfr[j] = *(const bf16x8*)&Bs[cur * 4096 + (wx * 64 + j * 16 + lm) * 32 + q * 8];
    #pragma unroll
    for (int i = 0; i < 4; i++)
      #pragma unroll
      for (int j = 0; j < 4; j++)
        acc[i][j] = __builtin_amdgcn_mfma_f32_16x16x32_bf16(af[i], bfr[j], acc[i][j], 0, 0, 0);
    __syncthreads();
    cur ^= 1;
  }
#undef PW_STAGE
  #pragma unroll
  for (int i = 0; i < 4; i++){
    #pragma unroll
    for (int r = 0; r < 4; r++){
      int row = m0 + wy * 64 + i * 16 + q * 4 + r;
      u16* cp = C + (size_t)row * HW + n0 + wx * 64 + lm;
      #pragma unroll
      for (int j = 0; j < 4; j++)
        cp[j * 16] = f2bf(acc[i][j][r]);
    }
  }
}

// ---------- K2: depthwise 3x3, one block per channel, vectorized ----------
__device__ __forceinline__ void loadrow(const u16* __restrict__ src, int r, int cg, float* o){
  if ((unsigned)r >= IMG){
    #pragma unroll
    for (int i = 0; i < 18; i++) o[i] = 0.f;
    return;
  }
  const u16* p = src + (size_t)r * IMG + cg * 16;
  uint4 v0 = *(const uint4*)p;
  uint4 v1 = *(const uint4*)(p + 8);
  u32 ww[8] = {v0.x, v0.y, v0.z, v0.w, v1.x, v1.y, v1.z, v1.w};
  #pragma unroll
  for (int i = 0; i < 8; i++){
    union { u32 u; float f; } lo, hi;
    lo.u = ww[i] << 16;
    hi.u = ww[i] & 0xffff0000u;
    o[1 + 2 * i] = lo.f;
    o[2 + 2 * i] = hi.f;
  }
  o[0]  = (cg > 0) ? bf2f(p[-1]) : 0.f;
  o[17] = (cg < 7) ? bf2f(p[16]) : 0.f;
}

__global__ void __launch_bounds__(256) k_dw2(const u16* __restrict__ T,
                                             const float* __restrict__ dw,
                                             u16* __restrict__ qdst,
                                             u16* __restrict__ vdst,
                                             float* __restrict__ ssq){
  int ch = blockIdx.x;
  const u16* src = T + (size_t)ch * HW;
  u16* dst = (ch < 2 * CDIM) ? qdst + (size_t)ch * HW
                             : vdst + (size_t)(ch - 2 * CDIM) * HW;
  float w[9];
  #pragma unroll
  for (int t = 0; t < 9; t++) w[t] = dw[ch * 9 + t];
  int tid = threadIdx.x;
  int rg = tid >> 3, cg = tid & 7;   // rows rg*4..+4, cols cg*16..+16
  float ss = 0.f;
  #pragma unroll
  for (int rr = 0; rr < 4; rr++){
    int r = rg * 4 + rr;
    float a[18], b[18], c[18];
    loadrow(src, r - 1, cg, a);
    loadrow(src, r,     cg, b);
    loadrow(src, r + 1, cg, c);
    u32 pk[8];
    #pragma unroll
    for (int x = 0; x < 16; x++){
      float acc = w[0] * a[x];
      acc = fmaf(w[1], a[x + 1], acc);
      acc = fmaf(w[2], a[x + 2], acc);
      acc = fmaf(w[3], b[x],     acc);
      acc = fmaf(w[4], b[x + 1], acc);
      acc = fmaf(w[5], b[x + 2], acc);
      acc = fmaf(w[6], c[x],     acc);
      acc = fmaf(w[7], c[x + 1], acc);
      acc = fmaf(w[8], c[x + 2], acc);
      ss = fmaf(acc, acc, ss);
      u16 hv = f2bf(acc);
      if (x & 1) pk[x >> 1] |= (u32)hv << 16;
      else       pk[x >> 1]  = (u32)hv;
    }
    *(uint4*)(dst + (size_t)r * IMG + cg * 16)     = *(uint4*)&pk[0];
    *(uint4*)(dst + (size_t)r * IMG + cg * 16 + 8) = *(uint4*)&pk[4];
  }
  if (ch < 2 * CDIM){
    __shared__ float red[256];
    red[tid] = ss;
    __syncthreads();
    for (int s = 128; s > 0; s >>= 1){
      if (tid < s) red[tid] += red[tid + s];
      __syncthreads();
    }
    if (tid == 0) ssq[ch] = red[0];
  }
}

// ---------- K_vt: transpose v [c][n] -> Vt[n][d] (d-half split into qkvx/qkvm v-slots) ----------
// grid (128 n-blocks, 8 heads, 8 z). src = Bt[z] slice (dead after k_pw(z)).
__global__ void __launch_bounds__(256) k_vt(const u16* __restrict__ Bt,
                                            u16* __restrict__ qkvx,
                                            u16* __restrict__ qkvm){
  int z = blockIdx.z;
  int inp = z >> 2, b = z & 3;
  const u16* vcn = Bt + (size_t)z * HW * CDIM;
  int h = blockIdx.y;
  int n0 = blockIdx.x * 128;
  u16* vt = (h < 4 ? qkvx : qkvm) + ((size_t)b * QKVC + 2 * CDIM) * HW;  // [16384][384]
  int dbase = (h & 3) * 96 + inp * 48;
  __shared__ u16 tile[48][136];
  int tid = threadIdx.x;
  #pragma unroll
  for (int j = 0; j < 3; j++){
    int i = tid + j * 256;            // uint4 index < 768
    int row = i >> 4, c8 = i & 15;
    uint4 v = *(const uint4*)(vcn + (size_t)(h * 48 + row) * HW + n0 + c8 * 8);
    *(uint4*)&tile[row][c8 * 8] = v;
  }
  __syncthreads();
  int n = tid >> 1, half = tid & 1;
  u16* dstp = vt + (size_t)(n0 + n) * CDIM + dbase + half * 24;
  #pragma unroll
  for (int u = 0; u < 3; u++){
    u32 pk[4];
    #pragma unroll
    for (int p = 0; p < 4; p++){
      int c = half * 24 + u * 8 + p * 2;
      pk[p] = (u32)tile[c][n] | ((u32)tile[c + 1][n] << 16);
    }
    *(uint4*)(dstp + u * 8) = *(uint4*)pk;
  }
}

// ---------- K3: logits via MFMA, fragments straight from global ----------
#define LCHUNK 1024
__global__ void __launch_bounds__(256) k_logits_mfma(const u16* __restrict__ qkvx,
                                                     const u16* __restrict__ qkvm,
                                                     float* __restrict__ S){
  int nc = blockIdx.x;               // 0..15
  int bh = blockIdx.y;               // 0..31
  int b = bh & 3, h = bh >> 2;
  int tid = threadIdx.x;
  int w = tid >> 6, lane = tid & 63;
  int wy = w >> 1, wx = w & 1;
  int lm = lane & 15, quad = lane >> 4;

  const u16* ap[3]; const u16* bp[3];
  #pragma unroll
  for (int i = 0; i < 3; i++){
    int g = wy * 48 + i * 16 + lm;
    int c = (g < 48) ? g : g - 48;
    ap[i] = ((g < 48) ? qkvx : qkvm) + ((size_t)b * QKVC + h * CHD + c) * HW;
    int d = wx * 48 + i * 16 + lm;
    int cc = (d < 48) ? d : d - 48;
    bp[i] = ((d < 48) ? qkvx : qkvm) + ((size_t)b * QKVC + CDIM + h * CHD + cc) * HW;
  }
  f32x4 acc[3][3];
  #pragma unroll
  for (int i = 0; i < 3; i++)
    #pragma unroll
    for (int j = 0; j < 3; j++) acc[i][j] = (f32x4){0.f,0.f,0.f,0.f};

  int nbeg = nc * LCHUNK + quad * 8;
  int nend = nc * LCHUNK + LCHUNK;
  for (int n = nbeg; n < nend; n += 32){
    bf16x8 af[3], bfr[3];
    #pragma unroll
    for (int i = 0; i < 3; i++) af[i]  = *(const bf16x8*)(ap[i] + n);
    #pragma unroll
    for (int j = 0; j < 3; j++) bfr[j] = *(const bf16x8*)(bp[j] + n);
    #pragma unroll
    for (int i = 0; i < 3; i++)
      #pragma unroll
      for (int j = 0; j < 3; j++)
        acc[i][j] = __builtin_amdgcn_mfma_f32_16x16x32_bf16(af[i], bfr[j], acc[i][j], 0, 0, 0);
  }
  #pragma unroll
  for (int i = 0; i < 3; i++){
    #pragma unroll
    for (int r = 0; r < 4; r++){
      int g = wy * 48 + i * 16 + quad * 4 + r;
      int iq = (g >= 48) ? 1 : 0;
      int c = iq ? g - 48 : g;
      float* Sp = S + (((size_t)(iq * BATCH + b) * NHEADS + h) * CHD + c) * DD2;
      #pragma unroll
      for (int j = 0; j < 3; j++)
        atomicAdd(&Sp[wx * 48 + j * 16 + lm], acc[i][j][r]);
    }
  }
}

// ---------- K4a: scale by norms+temperature, softmax over d ----------
__global__ void __launch_bounds__(128) k_softmax(const float* __restrict__ S,
                                                 const float* __restrict__ ssq,
                                                 const float* __restrict__ temp,
                                                 float* __restrict__ attn){
  int row = blockIdx.x;
  int c = row % CHD;
  int h = (row / CHD) % NHEADS;
  int b = (row / (CHD * NHEADS)) % BATCH;
  int iq = row / (CHD * NHEADS * BATCH);
  int tid = threadIdx.x;
  __shared__ float sh[128];
  const float* Sp = S + (size_t)row * DD2;
  float ssq_q = ssq[(iq * BATCH + b) * QKVC + h * CHD + c];
  float nq = fmaxf(sqrtf(ssq_q), 1e-12f);
  float tmp = temp[h];
  float logit = -1e30f;
  int d = tid;
  if (d < DD2){
    float ssq_k = ssq[((d < CHD ? 0 : 1) * BATCH + b) * QKVC + CDIM + h * CHD + (d % CHD)];
    float nk = fmaxf(sqrtf(ssq_k), 1e-12f);
    logit = Sp[d] * tmp / (nq * nk);
  }
  sh[tid] = logit; __syncthreads();
  for (int s = 64; s > 0; s >>= 1){
    if (tid < s) sh[tid] = fmaxf(sh[tid], sh[tid + s]);
    __syncthreads();
  }
  float mx = sh[0]; __syncthreads();
  float e = (d < DD2) ? expf(logit - mx) : 0.f;
  sh[tid] = e; __syncthreads();
  for (int s = 64; s > 0; s >>= 1){
    if (tid < s) sh[tid] += sh[tid + s];
    __syncthreads();
  }
  float sum = sh[0];
  if (d < DD2) attn[(size_t)row * DD2 + d] = e / sum;
}

// ---------- K4b: AfinB (bf16) = W2-folded attention ----------
__global__ void __launch_bounds__(128) k_mmat(const float* __restrict__ attn,
                                              const float* __restrict__ W2,
                                              u16* __restrict__ AfinB){
  int oz = blockIdx.x;
  int h = blockIdx.y;
  int b = blockIdx.z;
  __shared__ float a1[CHD * DD2];
  __shared__ float a2[CHD * DD2];
  int tid = threadIdx.x;
  const float* A1 = attn + ((size_t)(0 * BATCH + b) * NHEADS + h) * CHD * DD2;
  const float* A2 = attn + ((size_t)(1 * BATCH + b) * NHEADS + h) * CHD * DD2;
  for (int i = tid; i < CHD * DD2; i += 128){ a1[i] = A1[i]; a2[i] = A2[i]; }
  __syncthreads();
  int e = tid;
  if (e < DD2){
    for (int oo = 0; oo < 8; oo++){
      int o = oz * 8 + oo;
      float acc = 0.f;
      #pragma unroll 4
      for (int cc = 0; cc < CHD; cc++){
        acc = fmaf(W2[o * KFIN + h * CHD + cc],        a1[cc * DD2 + e], acc);
        acc = fmaf(W2[o * KFIN + CDIM + h * CHD + cc], a2[cc * DD2 + e], acc);
      }
      AfinB[((size_t)b * CDIM + o) * KFIN + h * DD2 + e] = f2bf(acc);
    }
  }
}

// ---------- K_fin: out[b][384][16384] = AfinB[b] @ Vt[b]^T + b2 ----------
// A [384][768] k-contig; B = Vt split: hp=0 -> qkvx v-slot [n][384], hp=1 -> qkvm v-slot.
__global__ void __launch_bounds__(256) k_fin(const u16* __restrict__ AfB,
                                             const u16* __restrict__ qkvx,
                                             const u16* __restrict__ qkvm,
                                             const float* __restrict__ b2,
                                             float* __restrict__ out){
  __shared__ __align__(16) u16 As[2 * 4096];
  __shared__ __align__(16) u16 Bs[2 * 4096];
  int orig = blockIdx.x;
  int swz = (orig & 7) * 192 + (orig >> 3);   // bijective: 1536 % 8 == 0
  int m = swz % 3;
  int rest = swz / 3;
  int n0 = (rest & 127) * 128;
  int bz = rest >> 7;
  int m0 = m * 128;
  int tid = threadIdx.x;
  int w = tid >> 6, lane = tid & 63;
  int wy = w >> 1, wx = w & 1;
  int lm = lane & 15, q = lane >> 4;

  int srow = w * 16 + (lane >> 2);
  int scol = (lane & 3) * 8;
  const u16* A = AfB + (size_t)bz * CDIM * KFIN;
  const u16* ga  = A + (size_t)(m0 + srow) * KFIN + scol;
  const u16* gb0 = qkvx + ((size_t)bz * QKVC + 2 * CDIM) * HW + (size_t)(n0 + srow) * CDIM + scol;
  const u16* gb1 = qkvm + ((size_t)bz * QKVC + 2 * CDIM) * HW + (size_t)(n0 + srow) * CDIM + scol;
  u16* la = As + srow * 32 + scol;
  u16* lb = Bs + srow * 32 + scol;

  f32x4 acc[4][4];
  #pragma unroll
  for (int i = 0; i < 4; i++)
    #pragma unroll
    for (int j = 0; j < 4; j++) acc[i][j] = (f32x4){0.f,0.f,0.f,0.f};

#define FIN_STAGE(buf, t) do{ \
    int hp_ = (t) >= 12; \
    int k0_ = ((t) - hp_ * 12) * 32; \
    const u16* gb_ = hp_ ? gb1 : gb0; \
    gl_lds16(ga + hp_ * CDIM + k0_,            la + (buf) * 4096); \
    gl_lds16(ga + hp_ * CDIM + k0_ + 64*KFIN,  la + (buf) * 4096 + 2048); \
    gl_lds16(gb_ + k0_,                        lb + (buf) * 4096); \
    gl_lds16(gb_ + k0_ + 64*CDIM,              lb + (buf) * 4096 + 2048); \
  }while(0)

  FIN_STAGE(0, 0);
  __syncthreads();
  int cur = 0;
  for (int t = 0; t < 24; t++){
    if (t < 23) FIN_STAGE(cur ^ 1, t + 1);
    bf16x8 af[4], bfr[4];
    #pragma unroll
    for (int i = 0; i < 4; i++)
      af[i] = *(const bf16x8*)&As[cur * 4096 + (wy * 64 + i * 16 + lm) * 32 + q * 8];
    #pragma unroll
    for (int j = 0; j < 4; j++)
      bfr[j] = *(const bf16x8*)&Bs[cur * 4096 + (wx * 64 + j * 16 + lm) * 32 + q * 8];
    #pragma unroll
    for (int i = 0; i < 4; i++)
      #pragma unroll
      for (int j = 0; j < 4; j++)
        acc[i][j] = __builtin_amdgcn_mfma_f32_16x16x32_bf16(af[i], bfr[j], acc[i][j], 0, 0, 0);
    __syncthreads();
    cur ^= 1;
  }
#undef FIN_STAGE
  #pragma unroll
  for (int i = 0; i < 4; i++){
    #pragma unroll
    for (int r = 0; r < 4; r++){
      int row = m0 + wy * 64 + i * 16 + q * 4 + r;
      float bv = b2[row];
      float* cp = out + (size_t)bz * CDIM * HW + (size_t)row * HW + n0 + wx * 64 + lm;
      #pragma unroll
      for (int j = 0; j < 4; j++)
        cp[j * 16] = acc[i][j][r] + bv;
    }
  }
}

extern "C" void kernel_launch(void* const* d_in, const int* in_sizes, int n_in,
                              void* d_out, int out_size, void* d_ws, size_t ws_size,
                              hipStream_t stream){
  const float* x      = (const float*)d_in[0];
  const float* msg    = (const float*)d_in[1];
  const float* temp   = (const float*)d_in[2];
  const float* qkv_w  = (const float*)d_in[3];
  const float* dw_w   = (const float*)d_in[4];
  const float* proj_w = (const float*)d_in[5];
  const float* lin_w  = (const float*)d_in[6];
  const float* lin_b  = (const float*)d_in[7];
  float* out = (float*)d_out;

  char* ws = (char*)d_ws;
  u16*   qkvx  = (u16*)(ws + OFF_QKVX);
  u16*   qkvm  = (u16*)(ws + OFF_QKVM);
  u16*   T     = (u16*)(ws + OFF_T);
  float* ssq   = (float*)(ws + OFF_SSQ);
  float* S     = (float*)(ws + OFF_S);
  float* attn  = (float*)(ws + OFF_ATTN);
  u16*   AfinB = (u16*)(ws + OFF_AFINB);
  float* W2    = (float*)(ws + OFF_W2);
  float* b2    = (float*)(ws + OFF_B2);
  u16*   Wb    = (u16*)(ws + OFF_WB);

  // Bt scratch lives in d_out (exactly out_size). Timeline per z:
  //   k_cvt writes Bt[z] -> k_pw(z) reads Bt[z] -> k_dw2(z) overwrites Bt[z] with v [c][n]
  //   -> k_vt reads it -> k_fin finally overwrites d_out with the real output.
  u16* Bt = (u16*)d_out;

  hipMemsetAsync(ws + OFF_S, 0, (OFF_ATTN - OFF_S), stream);

  k_w2<<<dim3((QKVC * CDIM + 255) / 256), dim3(256), 0, stream>>>(
      proj_w, lin_w, lin_b, qkv_w, W2, b2, Wb);

  k_cvt<<<dim3(HW / 64, CDIM / 64, 8), dim3(256), 0, stream>>>(x, msg, Bt);

  for (int z = 0; z < 8; z++){
    int inp = z >> 2, bb = z & 3;
    u16* qdst = (inp ? qkvm : qkvx) + (size_t)bb * QKVC * HW;
    k_pw<<<dim3(QKVC / 128 * (HW / 128)), dim3(256), 0, stream>>>(
        Wb, Bt + (size_t)z * HW * CDIM, T);
    k_dw2<<<dim3(QKVC), dim3(256), 0, stream>>>(
        T, dw_w, qdst, Bt + (size_t)z * HW * CDIM, ssq + (size_t)z * QKVC);
  }

  k_vt<<<dim3(HW / 128, 8, 8), dim3(256), 0, stream>>>(Bt, qkvx, qkvm);

  k_logits_mfma<<<dim3(16, 32), dim3(256), 0, stream>>>(qkvx, qkvm, S);
  k_softmax<<<dim3(2 * BATCH * NHEADS * CHD), dim3(128), 0, stream>>>(S, ssq, temp, attn);
  k_mmat<<<dim3(CDIM / 8, NHEADS, BATCH), dim3(128), 0, stream>>>(attn, W2, AfinB);
  k_fin<<<dim3(3 * (HW / 128) * BATCH), dim3(256), 0, stream>>>(
      AfinB, qkvx, qkvm, b2, out);
}

// Round 3
// 843.347 us; speedup vs baseline: 1.3760x; 1.2057x over previous
//
#include <hip/hip_runtime.h>

typedef unsigned short u16;
typedef unsigned int u32;

#define BATCH 4
#define CDIM 384
#define IMG 128
#define HW 16384
#define QKVC 1152
#define NHEADS 8
#define CHD 48
#define DD2 96
#define KFIN 768

typedef __attribute__((ext_vector_type(8))) short bf16x8;
typedef __attribute__((ext_vector_type(4))) float f32x4;

// ---------- bf16 helpers (manual RNE) ----------
__device__ __forceinline__ u16 f2bf(float f){
  union { float f; u32 u; } v; v.f = f;
  u32 u = v.u;
  u32 r = (u + 0x7fffu + ((u >> 16) & 1u)) >> 16;
  return (u16)r;
}
__device__ __forceinline__ float bf2f(u16 h){
  union { u32 u; float f; } v; v.u = ((u32)h) << 16;
  return v.f;
}

// ---------- workspace layout (bytes) ----------
#define OFF_QKVX  ((size_t)0)                         // u16 [4][1152][16384]; v-slot (rows 768..1151) holds Vt0 at end
#define OFF_QKVM  ((size_t)150994944)                 // u16 [4][1152][16384]; v-slot = T parity-1 scratch during loop, Vt1 at end
#define OFF_T     ((size_t)301989888)                 // u16 [1152][16384] = T parity-0
#define OFF_SSQ   ((size_t)339738624)                 // f32 [2][4][1152] (only ch<768 written/read)
#define OFF_S     ((size_t)339775488)                 // f32 [2][4][8][48][96]
#define OFF_ATTN  ((size_t)340955136)                 // f32 [2][4][8][48][96]
#define OFF_AFINB ((size_t)342134784)                 // bf16 [4][384][768]
#define OFF_W2    ((size_t)344494080)                 // f32 [384][768]
#define OFF_B2    ((size_t)345673728)                 // f32 [384]
#define OFF_WB    ((size_t)345675264)                 // bf16 [1152][384]

// ---------- global_load_lds helper (16B per lane, dest = base + lane*16) ----------
typedef __attribute__((address_space(1))) const u32 gas_u32;
typedef __attribute__((address_space(3))) u32 las_u32;
__device__ __forceinline__ void gl_lds16(const u16* g, u16* l){
  __builtin_amdgcn_global_load_lds((gas_u32*)g, (las_u32*)l, 16, 0, 0);
}

// ---------- T ping-pong row addressing ----------
// parity 0: contiguous T0 region. parity 1: qkvm v-row slots of b'=0..2 (dead until k_tail's vt).
__device__ __forceinline__ u16* t_row(u16* T0, u16* qkvm, int par, int ch){
  if (par == 0) return T0 + (size_t)ch * HW;
  int bq = ch / 384;
  int rr = ch - bq * 384;
  return qkvm + ((size_t)bq * QKVC + 2 * CDIM + rr) * HW;
}

// ---------- K0: W2 = proj_w @ lin_w ; b2 = proj_w @ lin_b ; Wb = bf16(qkv_w) ----------
__global__ void __launch_bounds__(256) k_w2(const float* __restrict__ proj,
                                            const float* __restrict__ lin,
                                            const float* __restrict__ linb,
                                            const float* __restrict__ qkvw,
                                            float* __restrict__ W2,
                                            float* __restrict__ b2,
                                            u16* __restrict__ Wb){
  int idx = blockIdx.x * 256 + threadIdx.x;
  if (idx < CDIM * KFIN){
    int o = idx / KFIN, d = idx % KFIN;
    float acc = 0.f;
    for (int c = 0; c < CDIM; c++)
      acc = fmaf(proj[o * CDIM + c], lin[c * KFIN + d], acc);
    W2[idx] = acc;
  }
  if (idx < CDIM){
    float acc = 0.f;
    for (int c = 0; c < CDIM; c++)
      acc = fmaf(proj[idx * CDIM + c], linb[c], acc);
    b2[idx] = acc;
  }
  if (idx < QKVC * CDIM) Wb[idx] = f2bf(qkvw[idx]);
}

// ---------- depthwise row loader (18-wide halo row, vectorized) ----------
__device__ __forceinline__ void loadrow(const u16* __restrict__ src, int r, int cg, float* o){
  if ((unsigned)r >= IMG){
    #pragma unroll
    for (int i = 0; i < 18; i++) o[i] = 0.f;
    return;
  }
  const u16* p = src + (size_t)r * IMG + cg * 16;
  uint4 v0 = *(const uint4*)p;
  uint4 v1 = *(const uint4*)(p + 8);
  u32 ww[8] = {v0.x, v0.y, v0.z, v0.w, v1.x, v1.y, v1.z, v1.w};
  #pragma unroll
  for (int i = 0; i < 8; i++){
    union { u32 u; float f; } lo, hi;
    lo.u = ww[i] << 16;
    hi.u = ww[i] & 0xffff0000u;
    o[1 + 2 * i] = lo.f;
    o[2 + 2 * i] = hi.f;
  }
  o[0]  = (cg > 0) ? bf2f(p[-1]) : 0.f;
  o[17] = (cg < 7) ? bf2f(p[16]) : 0.f;
}

// ---------- K_stage: fat pipelined dispatch. roles: [pw(t-1) | dw(t-2) | cvt(t)] ----------
__global__ void __launch_bounds__(256) k_stage(
    int t, int npw, int ndw,
    const u16* __restrict__ Wb, u16* __restrict__ Bt,
    u16* __restrict__ T0, u16* __restrict__ qkvx, u16* __restrict__ qkvm,
    const float* __restrict__ x, const float* __restrict__ msg,
    const float* __restrict__ dww, float* __restrict__ ssq){
  __shared__ __align__(16) u16 smem[16384];   // 32 KB, aliased per role
  int bid = blockIdx.x;
  int tid = threadIdx.x;

  if (bid < npw){
    // ======== role PW: T[par] = Wb @ Bt[z]^T,  z = t-1 ========
    int z = t - 1, par = z & 1;
    const u16* B = Bt + (size_t)z * HW * CDIM;
    u16* As = smem;            // [2][4096] u16
    u16* Bs = smem + 8192;
    int swz = (bid & 7) * 144 + (bid >> 3);   // bijective XCD swizzle (1152 % 8 == 0)
    int bx = swz % 9, by = swz / 9;
    int m0 = bx * 128, n0 = by * 128;
    int w = tid >> 6, lane = tid & 63;
    int wy = w >> 1, wx = w & 1;
    int lm = lane & 15, q = lane >> 4;

    int srow = w * 16 + (lane >> 2);
    int scol = (lane & 3) * 8;
    const u16* ga = Wb + (size_t)(m0 + srow) * CDIM + scol;
    const u16* gb = B + (size_t)(n0 + srow) * CDIM + scol;
    u16* la = As + srow * 32 + scol;
    u16* lb = Bs + srow * 32 + scol;

    f32x4 acc[4][4];
    #pragma unroll
    for (int i = 0; i < 4; i++)
      #pragma unroll
      for (int j = 0; j < 4; j++) acc[i][j] = (f32x4){0.f,0.f,0.f,0.f};

#define PW_STAGE(buf, k0) do{ \
      gl_lds16(ga + (k0),             la + (buf) * 4096); \
      gl_lds16(ga + 64*CDIM + (k0),   la + (buf) * 4096 + 2048); \
      gl_lds16(gb + (k0),             lb + (buf) * 4096); \
      gl_lds16(gb + 64*CDIM + (k0),   lb + (buf) * 4096 + 2048); \
    }while(0)

    PW_STAGE(0, 0);
    __syncthreads();
    int cur = 0;
    for (int kt = 0; kt < 12; kt++){
      if (kt < 11) PW_STAGE(cur ^ 1, (kt + 1) * 32);
      bf16x8 af[4], bfr[4];
      #pragma unroll
      for (int i = 0; i < 4; i++)
        af[i] = *(const bf16x8*)&As[cur * 4096 + (wy * 64 + i * 16 + lm) * 32 + q * 8];
      #pragma unroll
      for (int j = 0; j < 4; j++)
        bfr[j] = *(const bf16x8*)&Bs[cur * 4096 + (wx * 64 + j * 16 + lm) * 32 + q * 8];
      #pragma unroll
      for (int i = 0; i < 4; i++)
        #pragma unroll
        for (int j = 0; j < 4; j++)
          acc[i][j] = __builtin_amdgcn_mfma_f32_16x16x32_bf16(af[i], bfr[j], acc[i][j], 0, 0, 0);
      __syncthreads();
      cur ^= 1;
    }
#undef PW_STAGE
    #pragma unroll
    for (int i = 0; i < 4; i++){
      #pragma unroll
      for (int r = 0; r < 4; r++){
        int row = m0 + wy * 64 + i * 16 + q * 4 + r;
        u16* cp = t_row(T0, qkvm, par, row) + n0 + wx * 64 + lm;
        #pragma unroll
        for (int j = 0; j < 4; j++)
          cp[j * 16] = f2bf(acc[i][j][r]);
      }
    }

  } else if (bid < npw + ndw){
    // ======== role DW: depthwise 3x3 on T[z&1], z = t-2 ========
    int ch = bid - npw;
    int z = t - 2, par = z & 1;
    const u16* src = t_row(T0, qkvm, par, ch);
    u16* dst;
    if (ch < 2 * CDIM){
      u16* qd = ((z >> 2) ? qkvm : qkvx) + (size_t)(z & 3) * QKVC * HW;
      dst = qd + (size_t)ch * HW;
    } else {
      dst = Bt + (size_t)z * HW * CDIM + (size_t)(ch - 2 * CDIM) * HW;
    }
    float w[9];
    #pragma unroll
    for (int t9 = 0; t9 < 9; t9++) w[t9] = dww[ch * 9 + t9];
    int rg = tid >> 3, cg = tid & 7;
    int r0 = rg * 4;
    float ra[18], rb[18], rc[18];
    loadrow(src, r0 - 1, cg, ra);
    loadrow(src, r0,     cg, rb);
    float ss = 0.f;
    #pragma unroll
    for (int rr = 0; rr < 4; rr++){
      int r = r0 + rr;
      loadrow(src, r + 1, cg, rc);
      u32 pk[8];
      #pragma unroll
      for (int xx = 0; xx < 16; xx++){
        float a2 = w[0] * ra[xx];
        a2 = fmaf(w[1], ra[xx + 1], a2);
        a2 = fmaf(w[2], ra[xx + 2], a2);
        a2 = fmaf(w[3], rb[xx],     a2);
        a2 = fmaf(w[4], rb[xx + 1], a2);
        a2 = fmaf(w[5], rb[xx + 2], a2);
        a2 = fmaf(w[6], rc[xx],     a2);
        a2 = fmaf(w[7], rc[xx + 1], a2);
        a2 = fmaf(w[8], rc[xx + 2], a2);
        ss = fmaf(a2, a2, ss);
        u16 hv = f2bf(a2);
        if (xx & 1) pk[xx >> 1] |= (u32)hv << 16;
        else        pk[xx >> 1]  = (u32)hv;
      }
      *(uint4*)(dst + (size_t)r * IMG + cg * 16)     = *(uint4*)&pk[0];
      *(uint4*)(dst + (size_t)r * IMG + cg * 16 + 8) = *(uint4*)&pk[4];
      #pragma unroll
      for (int ii = 0; ii < 18; ii++){ ra[ii] = rb[ii]; rb[ii] = rc[ii]; }
    }
    if (ch < 2 * CDIM){
      float* red = (float*)smem;
      red[tid] = ss;
      __syncthreads();
      for (int s = 128; s > 0; s >>= 1){
        if (tid < s) red[tid] += red[tid + s];
        __syncthreads();
      }
      if (tid == 0) ssq[(size_t)z * QKVC + ch] = red[0];
    }

  } else {
    // ======== role CVT: fp32 [c][n] -> bf16 [n][c] into Bt[z], z = t ========
    int cb = bid - npw - ndw;          // 0..767
    int z = t;
    const float* src = (z < 4 ? x : msg) + (size_t)(z & 3) * CDIM * HW;
    u16* dstz = Bt + (size_t)z * HW * CDIM;
    int n0 = (cb & 127) * 128;
    int c0 = (cb >> 7) * 64;
    u16 (*tile)[130] = (u16(*)[130])smem;   // 64 x 130 u16 (pad 2 -> 260 B row stride)
    #pragma unroll
    for (int i = 0; i < 8; i++){
      int c = (tid >> 5) + i * 8;
      int nq = tid & 31;
      float4 v = *(const float4*)(src + (size_t)(c0 + c) * HW + n0 + nq * 4);
      u32 p0 = (u32)f2bf(v.x) | ((u32)f2bf(v.y) << 16);
      u32 p1 = (u32)f2bf(v.z) | ((u32)f2bf(v.w) << 16);
      *(u32*)&tile[c][nq * 4]     = p0;
      *(u32*)&tile[c][nq * 4 + 2] = p1;
    }
    __syncthreads();
    #pragma unroll
    for (int u = 0; u < 2; u++){
      int idx = tid + u * 256;            // 0..511
      int n = idx >> 2, j = idx & 3;
      u32 pk[8];
      #pragma unroll
      for (int p = 0; p < 8; p++)
        pk[p] = (u32)tile[j * 16 + 2 * p][n] | ((u32)tile[j * 16 + 2 * p + 1][n] << 16);
      u16* dp = dstz + (size_t)(n0 + n) * CDIM + c0 + j * 16;
      *(uint4*)dp       = *(uint4*)&pk[0];
      *(uint4*)(dp + 8) = *(uint4*)&pk[4];
    }
  }
}

// ---------- K_tail: fused [logits (512 blocks) | v-transpose (8192 blocks)] ----------
#define LCHUNK 1024
__global__ void __launch_bounds__(256) k_tail(u16* __restrict__ qkvx,
                                              u16* __restrict__ qkvm,
                                              float* __restrict__ S,
                                              const u16* __restrict__ Bt){
  __shared__ u16 tile[48][136];
  int bid = blockIdx.x;
  int tid = threadIdx.x;

  if (bid < 512){
    // ---- logits: S += q-frag . k-frag over n chunk ----
    int nc = bid & 15;
    int bh = bid >> 4;
    int b = bh & 3, h = bh >> 2;
    int w = tid >> 6, lane = tid & 63;
    int wy = w >> 1, wx = w & 1;
    int lm = lane & 15, quad = lane >> 4;

    const u16* ap[3]; const u16* bp[3];
    #pragma unroll
    for (int i = 0; i < 3; i++){
      int g = wy * 48 + i * 16 + lm;
      int c = (g < 48) ? g : g - 48;
      ap[i] = ((g < 48) ? qkvx : qkvm) + ((size_t)b * QKVC + h * CHD + c) * HW;
      int d = wx * 48 + i * 16 + lm;
      int cc = (d < 48) ? d : d - 48;
      bp[i] = ((d < 48) ? qkvx : qkvm) + ((size_t)b * QKVC + CDIM + h * CHD + cc) * HW;
    }
    f32x4 acc[3][3];
    #pragma unroll
    for (int i = 0; i < 3; i++)
      #pragma unroll
      for (int j = 0; j < 3; j++) acc[i][j] = (f32x4){0.f,0.f,0.f,0.f};

    int nbeg = nc * LCHUNK + quad * 8;
    int nend = nc * LCHUNK + LCHUNK;
    for (int n = nbeg; n < nend; n += 32){
      bf16x8 af[3], bfr[3];
      #pragma unroll
      for (int i = 0; i < 3; i++) af[i]  = *(const bf16x8*)(ap[i] + n);
      #pragma unroll
      for (int j = 0; j < 3; j++) bfr[j] = *(const bf16x8*)(bp[j] + n);
      #pragma unroll
      for (int i = 0; i < 3; i++)
        #pragma unroll
        for (int j = 0; j < 3; j++)
          acc[i][j] = __builtin_amdgcn_mfma_f32_16x16x32_bf16(af[i], bfr[j], acc[i][j], 0, 0, 0);
    }
    #pragma unroll
    for (int i = 0; i < 3; i++){
      #pragma unroll
      for (int r = 0; r < 4; r++){
        int g = wy * 48 + i * 16 + quad * 4 + r;
        int iq = (g >= 48) ? 1 : 0;
        int c = iq ? g - 48 : g;
        float* Sp = S + (((size_t)(iq * BATCH + b) * NHEADS + h) * CHD + c) * DD2;
        #pragma unroll
        for (int j = 0; j < 3; j++)
          atomicAdd(&Sp[wx * 48 + j * 16 + lm], acc[i][j][r]);
      }
    }
  } else {
    // ---- vt: v [c][n] (in Bt[z]) -> Vt[n][d] into qkvx/qkvm v-slots ----
    int v = bid - 512;
    int nb = v & 127;
    int h = (v >> 7) & 7;
    int z = v >> 10;
    int inp = z >> 2, b = z & 3;
    const u16* vcn = Bt + (size_t)z * HW * CDIM;
    int n0 = nb * 128;
    u16* vt = (h < 4 ? qkvx : qkvm) + ((size_t)b * QKVC + 2 * CDIM) * HW;  // [16384][384]
    int dbase = (h & 3) * 96 + inp * 48;
    #pragma unroll
    for (int j = 0; j < 3; j++){
      int i = tid + j * 256;            // uint4 index < 768
      int row = i >> 4, c8 = i & 15;
      uint4 vv = *(const uint4*)(vcn + (size_t)(h * 48 + row) * HW + n0 + c8 * 8);
      *(uint4*)&tile[row][c8 * 8] = vv;
    }
    __syncthreads();
    int n = tid >> 1, half = tid & 1;
    u16* dstp = vt + (size_t)(n0 + n) * CDIM + dbase + half * 24;
    #pragma unroll
    for (int u = 0; u < 3; u++){
      u32 pk[4];
      #pragma unroll
      for (int p = 0; p < 4; p++){
        int c = half * 24 + u * 8 + p * 2;
        pk[p] = (u32)tile[c][n] | ((u32)tile[c + 1][n] << 16);
      }
      *(uint4*)(dstp + u * 8) = *(uint4*)pk;
    }
  }
}

// ---------- K4a: scale by norms+temperature, softmax over d ----------
__global__ void __launch_bounds__(128) k_softmax(const float* __restrict__ S,
                                                 const float* __restrict__ ssq,
                                                 const float* __restrict__ temp,
                                                 float* __restrict__ attn){
  int row = blockIdx.x;
  int c = row % CHD;
  int h = (row / CHD) % NHEADS;
  int b = (row / (CHD * NHEADS)) % BATCH;
  int iq = row / (CHD * NHEADS * BATCH);
  int tid = threadIdx.x;
  __shared__ float sh[128];
  const float* Sp = S + (size_t)row * DD2;
  float ssq_q = ssq[(iq * BATCH + b) * QKVC + h * CHD + c];
  float nq = fmaxf(sqrtf(ssq_q), 1e-12f);
  float tmp = temp[h];
  float logit = -1e30f;
  int d = tid;
  if (d < DD2){
    float ssq_k = ssq[((d < CHD ? 0 : 1) * BATCH + b) * QKVC + CDIM + h * CHD + (d % CHD)];
    float nk = fmaxf(sqrtf(ssq_k), 1e-12f);
    logit = Sp[d] * tmp / (nq * nk);
  }
  sh[tid] = logit; __syncthreads();
  for (int s = 64; s > 0; s >>= 1){
    if (tid < s) sh[tid] = fmaxf(sh[tid], sh[tid + s]);
    __syncthreads();
  }
  float mx = sh[0]; __syncthreads();
  float e = (d < DD2) ? expf(logit - mx) : 0.f;
  sh[tid] = e; __syncthreads();
  for (int s = 64; s > 0; s >>= 1){
    if (tid < s) sh[tid] += sh[tid + s];
    __syncthreads();
  }
  float sum = sh[0];
  if (d < DD2) attn[(size_t)row * DD2 + d] = e / sum;
}

// ---------- K4b: AfinB (bf16) = W2-folded attention ----------
__global__ void __launch_bounds__(128) k_mmat(const float* __restrict__ attn,
                                              const float* __restrict__ W2,
                                              u16* __restrict__ AfinB){
  int oz = blockIdx.x;
  int h = blockIdx.y;
  int b = blockIdx.z;
  __shared__ float a1[CHD * DD2];
  __shared__ float a2[CHD * DD2];
  int tid = threadIdx.x;
  const float* A1 = attn + ((size_t)(0 * BATCH + b) * NHEADS + h) * CHD * DD2;
  const float* A2 = attn + ((size_t)(1 * BATCH + b) * NHEADS + h) * CHD * DD2;
  for (int i = tid; i < CHD * DD2; i += 128){ a1[i] = A1[i]; a2[i] = A2[i]; }
  __syncthreads();
  int e = tid;
  if (e < DD2){
    for (int oo = 0; oo < 8; oo++){
      int o = oz * 8 + oo;
      float acc = 0.f;
      #pragma unroll 4
      for (int cc = 0; cc < CHD; cc++){
        acc = fmaf(W2[o * KFIN + h * CHD + cc],        a1[cc * DD2 + e], acc);
        acc = fmaf(W2[o * KFIN + CDIM + h * CHD + cc], a2[cc * DD2 + e], acc);
      }
      AfinB[((size_t)b * CDIM + o) * KFIN + h * DD2 + e] = f2bf(acc);
    }
  }
}

// ---------- K_fin: out[b][384][16384] = AfinB[b] @ Vt[b]^T + b2 ----------
__global__ void __launch_bounds__(256) k_fin(const u16* __restrict__ AfB,
                                             const u16* __restrict__ qkvx,
                                             const u16* __restrict__ qkvm,
                                             const float* __restrict__ b2,
                                             float* __restrict__ out){
  __shared__ __align__(16) u16 As[2 * 4096];
  __shared__ __align__(16) u16 Bs[2 * 4096];
  int orig = blockIdx.x;
  int swz = (orig & 7) * 192 + (orig >> 3);   // bijective: 1536 % 8 == 0
  int m = swz % 3;
  int rest = swz / 3;
  int n0 = (rest & 127) * 128;
  int bz = rest >> 7;
  int m0 = m * 128;
  int tid = threadIdx.x;
  int w = tid >> 6, lane = tid & 63;
  int wy = w >> 1, wx = w & 1;
  int lm = lane & 15, q = lane >> 4;

  int srow = w * 16 + (lane >> 2);
  int scol = (lane & 3) * 8;
  const u16* A = AfB + (size_t)bz * CDIM * KFIN;
  const u16* ga  = A + (size_t)(m0 + srow) * KFIN + scol;
  const u16* gb0 = qkvx + ((size_t)bz * QKVC + 2 * CDIM) * HW + (size_t)(n0 + srow) * CDIM + scol;
  const u16* gb1 = qkvm + ((size_t)bz * QKVC + 2 * CDIM) * HW + (size_t)(n0 + srow) * CDIM + scol;
  u16* la = As + srow * 32 + scol;
  u16* lb = Bs + srow * 32 + scol;

  f32x4 acc[4][4];
  #pragma unroll
  for (int i = 0; i < 4; i++)
    #pragma unroll
    for (int j = 0; j < 4; j++) acc[i][j] = (f32x4){0.f,0.f,0.f,0.f};

#define FIN_STAGE(buf, t) do{ \
    int hp_ = (t) >= 12; \
    int k0_ = ((t) - hp_ * 12) * 32; \
    const u16* gb_ = hp_ ? gb1 : gb0; \
    gl_lds16(ga + hp_ * CDIM + k0_,            la + (buf) * 4096); \
    gl_lds16(ga + hp_ * CDIM + k0_ + 64*KFIN,  la + (buf) * 4096 + 2048); \
    gl_lds16(gb_ + k0_,                        lb + (buf) * 4096); \
    gl_lds16(gb_ + k0_ + 64*CDIM,              lb + (buf) * 4096 + 2048); \
  }while(0)

  FIN_STAGE(0, 0);
  __syncthreads();
  int cur = 0;
  for (int t = 0; t < 24; t++){
    if (t < 23) FIN_STAGE(cur ^ 1, t + 1);
    bf16x8 af[4], bfr[4];
    #pragma unroll
    for (int i = 0; i < 4; i++)
      af[i] = *(const bf16x8*)&As[cur * 4096 + (wy * 64 + i * 16 + lm) * 32 + q * 8];
    #pragma unroll
    for (int j = 0; j < 4; j++)
      bfr[j] = *(const bf16x8*)&Bs[cur * 4096 + (wx * 64 + j * 16 + lm) * 32 + q * 8];
    #pragma unroll
    for (int i = 0; i < 4; i++)
      #pragma unroll
      for (int j = 0; j < 4; j++)
        acc[i][j] = __builtin_amdgcn_mfma_f32_16x16x32_bf16(af[i], bfr[j], acc[i][j], 0, 0, 0);
    __syncthreads();
    cur ^= 1;
  }
#undef FIN_STAGE
  #pragma unroll
  for (int i = 0; i < 4; i++){
    #pragma unroll
    for (int r = 0; r < 4; r++){
      int row = m0 + wy * 64 + i * 16 + q * 4 + r;
      float bv = b2[row];
      float* cp = out + (size_t)bz * CDIM * HW + (size_t)row * HW + n0 + wx * 64 + lm;
      #pragma unroll
      for (int j = 0; j < 4; j++)
        cp[j * 16] = acc[i][j][r] + bv;
    }
  }
}

extern "C" void kernel_launch(void* const* d_in, const int* in_sizes, int n_in,
                              void* d_out, int out_size, void* d_ws, size_t ws_size,
                              hipStream_t stream){
  const float* x      = (const float*)d_in[0];
  const float* msg    = (const float*)d_in[1];
  const float* temp   = (const float*)d_in[2];
  const float* qkv_w  = (const float*)d_in[3];
  const float* dw_w   = (const float*)d_in[4];
  const float* proj_w = (const float*)d_in[5];
  const float* lin_w  = (const float*)d_in[6];
  const float* lin_b  = (const float*)d_in[7];
  float* out = (float*)d_out;

  char* ws = (char*)d_ws;
  u16*   qkvx  = (u16*)(ws + OFF_QKVX);
  u16*   qkvm  = (u16*)(ws + OFF_QKVM);
  u16*   T0    = (u16*)(ws + OFF_T);
  float* ssq   = (float*)(ws + OFF_SSQ);
  float* S     = (float*)(ws + OFF_S);
  float* attn  = (float*)(ws + OFF_ATTN);
  u16*   AfinB = (u16*)(ws + OFF_AFINB);
  float* W2    = (float*)(ws + OFF_W2);
  float* b2    = (float*)(ws + OFF_B2);
  u16*   Wb    = (u16*)(ws + OFF_WB);

  // Bt scratch lives in d_out (exactly out_size). Timeline per z (pipelined across dispatches):
  //   cvt(z) writes Bt[z] -> pw(z) reads Bt[z] -> dw(z) overwrites Bt[z] with v [c][n]
  //   -> k_tail's vt reads it -> k_fin finally overwrites d_out with the real output.
  u16* Bt = (u16*)d_out;

  hipMemsetAsync(ws + OFF_S, 0, (OFF_ATTN - OFF_S), stream);

  k_w2<<<dim3((QKVC * CDIM + 255) / 256), dim3(256), 0, stream>>>(
      proj_w, lin_w, lin_b, qkv_w, W2, b2, Wb);

  // 3-deep software pipeline: dispatch t runs pw(t-1) | dw(t-2) | cvt(t) concurrently.
  for (int t = 0; t < 10; t++){
    int npw  = (t >= 1 && t <= 8) ? 1152 : 0;
    int ndw  = (t >= 2) ? 1152 : 0;
    int ncvt = (t < 8) ? 768 : 0;
    k_stage<<<dim3(npw + ndw + ncvt), dim3(256), 0, stream>>>(
        t, npw, ndw, Wb, Bt, T0, qkvx, qkvm, x, msg, dw_w, ssq);
  }

  k_tail<<<dim3(512 + 8192), dim3(256), 0, stream>>>(qkvx, qkvm, S, Bt);
  k_softmax<<<dim3(2 * BATCH * NHEADS * CHD), dim3(128), 0, stream>>>(S, ssq, temp, attn);
  k_mmat<<<dim3(CDIM / 8, NHEADS, BATCH), dim3(128), 0, stream>>>(attn, W2, AfinB);
  k_fin<<<dim3(3 * (HW / 128) * BATCH), dim3(256), 0, stream>>>(
      AfinB, qkvx, qkvm, b2, out);
}